// Round 1
// baseline (782.982 us; speedup 1.0000x reference)
//
#include <hip/hip_runtime.h>
#include <math.h>

#define NN 20000
#define NE 320000
#define NB 128
#define DINC 64
#define NH 2
#define NC 64
#define SLOPE 0.2f
#define BN_EPS 1e-5f

__device__ __forceinline__ unsigned int enc_f(float f) {
    unsigned int b = __float_as_uint(f);
    return (b & 0x80000000u) ? ~b : (b | 0x80000000u);
}
__device__ __forceinline__ float dec_f(unsigned int u) {
    unsigned int b = (u & 0x80000000u) ? (u & 0x7FFFFFFFu) : ~u;
    return __uint_as_float(b);
}

// P1: v_e[h*64+k] = sum_c W_e[k, h*64+c]*att_e[h,c];  w2e[h*64+k] = sum_c W_e[64+k, h*64+c]*att_e[h,c]
__global__ __launch_bounds__(256) void k_p1(const float* __restrict__ We, const float* __restrict__ atte,
                                            float* __restrict__ ve, float* __restrict__ w2e) {
    int t = threadIdx.x;
    int h = (t >> 6) & 1;
    int k = t & 63;
    int row = (t < 128) ? k : (64 + k);
    float acc = 0.f;
    for (int c = 0; c < 64; ++c) acc += We[row * 128 + h * 64 + c] * atte[h * 64 + c];
    if (t < 128) ve[t] = acc; else w2e[t - 128] = acc;
}

// P2: blocks 0..63: insl[b*128+j] = sum_k ins[b,k]*W_l[64+k, j]; block 64: ce[b*2+h] = sum_k ins[b,k]*w2e[h*64+k]
__global__ __launch_bounds__(256) void k_p2(const float* __restrict__ ins, const float* __restrict__ Wl,
                                            const float* __restrict__ w2e,
                                            float* __restrict__ insl, float* __restrict__ ce) {
    int t = threadIdx.x;
    if (blockIdx.x < 64) {
        int idx = blockIdx.x * 256 + t;
        int b = idx >> 7, j = idx & 127;
        float acc = 0.f;
        for (int k = 0; k < 64; ++k) acc += ins[b * 64 + k] * Wl[(64 + k) * 128 + j];
        insl[idx] = acc;
    } else {
        int b = t >> 1, h = t & 1;
        float acc = 0.f;
        for (int k = 0; k < 64; ++k) acc += ins[b * 64 + k] * w2e[h * 64 + k];
        ce[t] = acc;
    }
}

// Node kernel: xl[n,128] = hcur[n,:]@Wl[:64] + insl[batch[n]]; al/ar reductions.
// Block = 256 thr = 4 waves; wave w: head h=w&1, rows (w>>1)*4 .. +3; 8 rows/block.
__global__ __launch_bounds__(256) void k_node(const float* __restrict__ hcur, const float* __restrict__ Wl,
                                              const float* __restrict__ insl, const int* __restrict__ batch,
                                              const float* __restrict__ attl, const float* __restrict__ attr_,
                                              float* __restrict__ xl, float* __restrict__ al, float* __restrict__ ar) {
    __shared__ float sh[8 * 64];
    int t = threadIdx.x;
    int row0 = blockIdx.x * 8;
    for (int idx = t; idx < 512; idx += 256) {
        int r = idx >> 6, k = idx & 63;
        int n = row0 + r;
        sh[idx] = (n < NN) ? hcur[n * 64 + k] : 0.f;
    }
    __syncthreads();
    int w = t >> 6, lane = t & 63;
    int h = w & 1;
    int rbase = (w >> 1) * 4;
    int j = h * 64 + lane;
    float attlv = attl[j];
    float attrv = attr_[j];
    float acc0 = 0.f, acc1 = 0.f, acc2 = 0.f, acc3 = 0.f;
    for (int k = 0; k < 64; ++k) {
        float wv = Wl[k * 128 + j];
        acc0 += sh[(rbase + 0) * 64 + k] * wv;
        acc1 += sh[(rbase + 1) * 64 + k] * wv;
        acc2 += sh[(rbase + 2) * 64 + k] * wv;
        acc3 += sh[(rbase + 3) * 64 + k] * wv;
    }
    float accs[4] = {acc0, acc1, acc2, acc3};
    for (int rr = 0; rr < 4; ++rr) {
        int n = row0 + rbase + rr;
        if (n >= NN) break;
        int b = batch[n];
        float v = accs[rr] + insl[b * 128 + j];
        xl[n * 128 + j] = v;
        float pl = v * attlv, pr = v * attrv;
        for (int off = 32; off > 0; off >>= 1) {
            pl += __shfl_xor(pl, off);
            pr += __shfl_xor(pr, off);
        }
        if (lane == 0) { al[n * 2 + h] = pl; ar[n * 2 + h] = pr; }
    }
}

// Edge pass A: one thread per edge. a[e,h] = leaky(al[s,h]+ar[d,h]+attr.ve[h]+ce[batch[s],h]); atomicMax m.
__global__ __launch_bounds__(256) void k_edgeA(const int* __restrict__ src, const int* __restrict__ dst,
                                               const float* __restrict__ eattr, const int* __restrict__ batch,
                                               const float* __restrict__ ve, const float* __restrict__ ce,
                                               const float* __restrict__ al, const float* __restrict__ ar,
                                               float* __restrict__ a_out, unsigned int* __restrict__ m_enc) {
    __shared__ float sv[128];
    int t = threadIdx.x;
    if (t < 128) sv[t] = ve[t];
    __syncthreads();
    int e = blockIdx.x * 256 + t;
    if (e >= NE) return;
    int s = src[e], d = dst[e];
    int bs = batch[s];
    const float4* row = (const float4*)(eattr + (size_t)e * 64);
    float a0 = 0.f, a1 = 0.f;
#pragma unroll
    for (int q = 0; q < 16; ++q) {
        float4 f = row[q];
        a0 += f.x * sv[q * 4 + 0] + f.y * sv[q * 4 + 1] + f.z * sv[q * 4 + 2] + f.w * sv[q * 4 + 3];
        a1 += f.x * sv[64 + q * 4 + 0] + f.y * sv[64 + q * 4 + 1] + f.z * sv[64 + q * 4 + 2] + f.w * sv[64 + q * 4 + 3];
    }
    a0 += al[s * 2 + 0] + ar[d * 2 + 0] + ce[bs * 2 + 0];
    a1 += al[s * 2 + 1] + ar[d * 2 + 1] + ce[bs * 2 + 1];
    a0 = (a0 > 0.f) ? a0 : SLOPE * a0;
    a1 = (a1 > 0.f) ? a1 : SLOPE * a1;
    ((float2*)a_out)[e] = make_float2(a0, a1);
    atomicMax(&m_enc[d * 2 + 0], enc_f(a0));
    atomicMax(&m_enc[d * 2 + 1], enc_f(a1));
}

// Edge pass B: 2 edges/block, 128 lanes per edge (c dim). Unnormalized accumulation.
__global__ __launch_bounds__(256) void k_edgeB(const int* __restrict__ src, const int* __restrict__ dst,
                                               const float* __restrict__ a_in, const unsigned int* __restrict__ m_enc,
                                               const float* __restrict__ xl,
                                               float* __restrict__ ssum, float* __restrict__ out_acc) {
    int t = threadIdx.x;
    int e = blockIdx.x * 2 + (t >> 7);
    if (e >= NE) return;
    int c = t & 127;
    int h = c >> 6;
    int s = src[e], d = dst[e];
    float av = a_in[e * 2 + h];
    float m = dec_f(m_enc[d * 2 + h]);
    float ex = expf(av - m);
    if ((t & 63) == 0) atomicAdd(&ssum[d * 2 + h], ex);
    atomicAdd(&out_acc[(size_t)d * 128 + c], ex * xl[(size_t)s * 128 + c]);
}

// Finalize layer0: hnew = mean-head(out_acc/ssum) + bias + hprev; accumulate BN sums.
__global__ __launch_bounds__(256) void k_fin0(const float* __restrict__ out_acc, const float* __restrict__ ssum,
                                              const float* __restrict__ bias, const float* __restrict__ hprev,
                                              float* __restrict__ hnew, float* __restrict__ bnsum, float* __restrict__ bnsumsq) {
    __shared__ float sa[256], sb[256];
    int t = threadIdx.x;
    int r = t >> 6, c = t & 63;
    int n = blockIdx.x * 4 + r;
    float v = 0.f;
    if (n < NN) {
        float s0 = ssum[n * 2 + 0] + 1e-16f;
        float s1 = ssum[n * 2 + 1] + 1e-16f;
        v = 0.5f * (out_acc[(size_t)n * 128 + c] / s0 + out_acc[(size_t)n * 128 + 64 + c] / s1)
            + bias[c] + hprev[n * 64 + c];
        hnew[n * 64 + c] = v;
    }
    sa[t] = v; sb[t] = v * v;
    __syncthreads();
    if (t < 64) {
        float a = sa[t] + sa[t + 64] + sa[t + 128] + sa[t + 192];
        float b = sb[t] + sb[t + 64] + sb[t + 128] + sb[t + 192];
        atomicAdd(&bnsum[t], a);
        atomicAdd(&bnsumsq[t], b);
    }
}

// BN apply + relu (in place on hbuf)
__global__ __launch_bounds__(256) void k_bn(float* __restrict__ hbuf, const float* __restrict__ bnsum,
                                            const float* __restrict__ bnsumsq,
                                            const float* __restrict__ gamma, const float* __restrict__ beta) {
    int idx = blockIdx.x * 256 + threadIdx.x;
    if (idx >= NN * 64) return;
    int c = idx & 63;
    float mu = bnsum[c] * (1.f / NN);
    float var = bnsumsq[c] * (1.f / NN) - mu * mu;
    float v = (hbuf[idx] - mu) * rsqrtf(var + BN_EPS) * gamma[c] + beta[c];
    hbuf[idx] = (v > 0.f) ? v : 0.f;
}

// Finalize layer1: out = mean-head(out_acc/ssum) + bias + hprev -> d_out
__global__ __launch_bounds__(256) void k_fin1(const float* __restrict__ out_acc, const float* __restrict__ ssum,
                                              const float* __restrict__ bias, const float* __restrict__ hprev,
                                              float* __restrict__ out) {
    int idx = blockIdx.x * 256 + threadIdx.x;
    if (idx >= NN * 64) return;
    int n = idx >> 6, c = idx & 63;
    float s0 = ssum[n * 2 + 0] + 1e-16f;
    float s1 = ssum[n * 2 + 1] + 1e-16f;
    out[idx] = 0.5f * (out_acc[(size_t)n * 128 + c] / s0 + out_acc[(size_t)n * 128 + 64 + c] / s1)
               + bias[c] + hprev[idx];
}

extern "C" void kernel_launch(void* const* d_in, const int* in_sizes, int n_in,
                              void* d_out, int out_size, void* d_ws, size_t ws_size,
                              hipStream_t stream) {
    (void)in_sizes; (void)n_in; (void)out_size; (void)ws_size;
    const float* x      = (const float*)d_in[0];
    const int*   eidx   = (const int*)d_in[1];
    const float* eattr  = (const float*)d_in[2];
    const float* instr  = (const float*)d_in[3];
    const int*   batch  = (const int*)d_in[4];
    const float* W_l    = (const float*)d_in[5];
    const float* W_e    = (const float*)d_in[6];
    const float* att_l  = (const float*)d_in[7];
    const float* att_r  = (const float*)d_in[8];
    const float* att_e  = (const float*)d_in[9];
    const float* bias   = (const float*)d_in[10];
    const float* bn_g   = (const float*)d_in[11];
    const float* bn_b   = (const float*)d_in[12];
    float* out = (float*)d_out;

    const int* src = eidx;
    const int* dst = eidx + NE;

    float* ws = (float*)d_ws;
    float* xl      = ws;                      // N*128
    float* out_acc = xl + (size_t)NN * 128;   // N*128
    float* a_buf   = out_acc + (size_t)NN * 128; // E*2
    float* al      = a_buf + (size_t)NE * 2;  // N*2
    float* ar      = al + NN * 2;             // N*2
    float* ssum    = ar + NN * 2;             // N*2
    unsigned int* m_enc = (unsigned int*)(ssum + NN * 2); // N*2
    float* insl    = (float*)(m_enc + NN * 2);// 128*128
    float* ve      = insl + 128 * 128;        // 128
    float* w2e     = ve + 128;                // 128
    float* ce      = w2e + 128;               // 256
    float* hbuf    = ce + 256;                // N*64
    float* bnsum   = hbuf + (size_t)NN * 64;  // 64
    float* bnsumsq = bnsum + 64;              // 64

    for (int i = 0; i < 2; ++i) {
        const float* hcur = (i == 0) ? x : hbuf;
        hipMemsetAsync(out_acc, 0, (size_t)NN * 128 * 4, stream);
        hipMemsetAsync(ssum, 0, NN * 2 * 4, stream);
        hipMemsetAsync(m_enc, 0, NN * 2 * 4, stream);
        if (i == 0) hipMemsetAsync(bnsum, 0, 128 * 4, stream);

        const float* Wl_i = W_l + (size_t)i * 128 * 128;
        const float* We_i = W_e + (size_t)i * 128 * 128;
        const float* ins_i = instr + (size_t)i * NB * 64;

        k_p1<<<1, 256, 0, stream>>>(We_i, att_e + i * 128, ve, w2e);
        k_p2<<<65, 256, 0, stream>>>(ins_i, Wl_i, w2e, insl, ce);
        k_node<<<(NN + 7) / 8, 256, 0, stream>>>(hcur, Wl_i, insl, batch,
                                                 att_l + i * 128, att_r + i * 128, xl, al, ar);
        k_edgeA<<<(NE + 255) / 256, 256, 0, stream>>>(src, dst, eattr, batch, ve, ce, al, ar, a_buf, m_enc);
        k_edgeB<<<(NE + 1) / 2, 256, 0, stream>>>(src, dst, a_buf, m_enc, xl, ssum, out_acc);
        if (i == 0) {
            k_fin0<<<(NN + 3) / 4, 256, 0, stream>>>(out_acc, ssum, bias, x, hbuf, bnsum, bnsumsq);
            k_bn<<<(NN * 64 + 255) / 256, 256, 0, stream>>>(hbuf, bnsum, bnsumsq, bn_g, bn_b);
        } else {
            k_fin1<<<(NN * 64 + 255) / 256, 256, 0, stream>>>(out_acc, ssum, bias + 64, hbuf, out);
        }
    }
}

// Round 2
// 548.617 us; speedup vs baseline: 1.4272x; 1.4272x over previous
//
#include <hip/hip_runtime.h>
#include <math.h>

#define NN 20000
#define NE 320000
#define NB 128
#define SLOPE 0.2f
#define BN_EPS 1e-5f

// ---------- CSR build ----------
__global__ __launch_bounds__(256) void k_hist(const int* __restrict__ dst, int* __restrict__ deg) {
    int e = blockIdx.x * 256 + threadIdx.x;
    if (e < NE) atomicAdd(&deg[dst[e]], 1);
}

__global__ __launch_bounds__(256) void k_scan(const int* __restrict__ deg, int* __restrict__ rowptr,
                                              int* __restrict__ cursor) {
    __shared__ int ssum[256];
    __shared__ int soff[256];
    const int CH = 79; // 256*79 = 20224 >= NN
    int t = threadIdx.x;
    int base = t * CH;
    int s = 0;
    for (int i = 0; i < CH; ++i) { int idx = base + i; if (idx < NN) s += deg[idx]; }
    ssum[t] = s;
    __syncthreads();
    if (t == 0) {
        int run = 0;
        for (int i = 0; i < 256; ++i) { soff[i] = run; run += ssum[i]; }
        rowptr[NN] = run;
    }
    __syncthreads();
    int run = soff[t];
    for (int i = 0; i < CH; ++i) {
        int idx = base + i;
        if (idx < NN) { rowptr[idx] = run; cursor[idx] = run; run += deg[idx]; }
    }
}

// perm[e] = CSR slot; csr_sb[slot] = src | (batch[src] << 20)
__global__ __launch_bounds__(256) void k_scatter(const int* __restrict__ src, const int* __restrict__ dst,
                                                 const int* __restrict__ batch,
                                                 int* __restrict__ cursor, int* __restrict__ perm,
                                                 int* __restrict__ csr_sb) {
    int e = blockIdx.x * 256 + threadIdx.x;
    if (e >= NE) return;
    int d = dst[e];
    int pos = atomicAdd(&cursor[d], 1);
    perm[e] = pos;
    int s = src[e];
    csr_sb[pos] = s | (batch[s] << 20);
}

// ---------- per-layer precompute ----------
// blockIdx = layer. ve01[L*128 + h*64 + k] = sum_c W_e[L][k, h*64+c]*att_e[L][h,c]
// w2e01[L*128 + h*64 + k] = sum_c W_e[L][64+k, h*64+c]*att_e[L][h,c]
__global__ __launch_bounds__(256) void k_p1(const float* __restrict__ We, const float* __restrict__ atte,
                                            float* __restrict__ ve01, float* __restrict__ w2e01) {
    int L = blockIdx.x;
    const float* WeL = We + (size_t)L * 128 * 128;
    const float* aeL = atte + L * 128;
    int t = threadIdx.x;
    int h = (t >> 6) & 1;
    int k = t & 63;
    int row = (t < 128) ? k : (64 + k);
    float acc = 0.f;
    for (int c = 0; c < 64; ++c) acc += WeL[row * 128 + h * 64 + c] * aeL[h * 64 + c];
    if (t < 128) ve01[L * 128 + t] = acc;
    else        w2e01[L * 128 + (t - 128)] = acc;
}

// blocks 0..63: insl[b*128+j] = sum_k ins[b,k]*W_l[64+k, j]; block 64: ce[b*2+h]
__global__ __launch_bounds__(256) void k_p2(const float* __restrict__ ins, const float* __restrict__ Wl,
                                            const float* __restrict__ w2e,
                                            float* __restrict__ insl, float* __restrict__ ce) {
    int t = threadIdx.x;
    if (blockIdx.x < 64) {
        int idx = blockIdx.x * 256 + t;
        int b = idx >> 7, j = idx & 127;
        float acc = 0.f;
        for (int k = 0; k < 64; ++k) acc += ins[b * 64 + k] * Wl[(64 + k) * 128 + j];
        insl[idx] = acc;
    } else {
        int b = t >> 1, h = t & 1;
        float acc = 0.f;
        for (int k = 0; k < 64; ++k) acc += ins[b * 64 + k] * w2e[h * 64 + k];
        ce[t] = acc;
    }
}

// ---------- edge dot for BOTH layers, written in CSR order ----------
__global__ __launch_bounds__(256) void k_edot(const float* __restrict__ eattr, const int* __restrict__ perm,
                                              const float* __restrict__ ve01, float4* __restrict__ ae4) {
    __shared__ float sv[256];
    int t = threadIdx.x;
    sv[t] = ve01[t];
    __syncthreads();
    int e = blockIdx.x * 256 + t;
    if (e >= NE) return;
    const float4* row = (const float4*)(eattr + (size_t)e * 64);
    float a00 = 0.f, a01 = 0.f, a10 = 0.f, a11 = 0.f;
#pragma unroll
    for (int q = 0; q < 16; ++q) {
        float4 f = row[q];
        int k = q * 4;
        a00 += f.x * sv[k] + f.y * sv[k + 1] + f.z * sv[k + 2] + f.w * sv[k + 3];
        a01 += f.x * sv[64 + k] + f.y * sv[64 + k + 1] + f.z * sv[64 + k + 2] + f.w * sv[64 + k + 3];
        a10 += f.x * sv[128 + k] + f.y * sv[128 + k + 1] + f.z * sv[128 + k + 2] + f.w * sv[128 + k + 3];
        a11 += f.x * sv[192 + k] + f.y * sv[192 + k + 1] + f.z * sv[192 + k + 2] + f.w * sv[192 + k + 3];
    }
    ae4[perm[e]] = make_float4(a00, a01, a10, a11);
}

// ---------- node linear + attention coefficients ----------
__global__ __launch_bounds__(256) void k_node(const float* __restrict__ hcur, const float* __restrict__ Wl,
                                              const float* __restrict__ insl, const int* __restrict__ batch,
                                              const float* __restrict__ attl, const float* __restrict__ attr_,
                                              float* __restrict__ xl, float* __restrict__ al, float* __restrict__ ar) {
    __shared__ float sh[8 * 64];
    int t = threadIdx.x;
    int row0 = blockIdx.x * 8;
    for (int idx = t; idx < 512; idx += 256) {
        int r = idx >> 6, k = idx & 63;
        int n = row0 + r;
        sh[idx] = (n < NN) ? hcur[n * 64 + k] : 0.f;
    }
    __syncthreads();
    int w = t >> 6, lane = t & 63;
    int h = w & 1;
    int rbase = (w >> 1) * 4;
    int j = h * 64 + lane;
    float attlv = attl[j];
    float attrv = attr_[j];
    float acc0 = 0.f, acc1 = 0.f, acc2 = 0.f, acc3 = 0.f;
    for (int k = 0; k < 64; ++k) {
        float wv = Wl[k * 128 + j];
        acc0 += sh[(rbase + 0) * 64 + k] * wv;
        acc1 += sh[(rbase + 1) * 64 + k] * wv;
        acc2 += sh[(rbase + 2) * 64 + k] * wv;
        acc3 += sh[(rbase + 3) * 64 + k] * wv;
    }
    float accs[4] = {acc0, acc1, acc2, acc3};
    for (int rr = 0; rr < 4; ++rr) {
        int n = row0 + rbase + rr;
        if (n >= NN) break;
        int b = batch[n];
        float v = accs[rr] + insl[b * 128 + j];
        xl[(size_t)n * 128 + j] = v;
        float pl = v * attlv, pr = v * attrv;
        for (int off = 32; off > 0; off >>= 1) {
            pl += __shfl_xor(pl, off);
            pr += __shfl_xor(pr, off);
        }
        if (lane == 0) { al[n * 2 + h] = pl; ar[n * 2 + h] = pr; }
    }
}

// ---------- fused gather: softmax over incoming edges + weighted sum + finalize ----------
// 1 wave per node; lane = output channel. layer selects ae4 components.
__global__ __launch_bounds__(256) void k_nodeagg(const int* __restrict__ rowptr, const int* __restrict__ csr_sb,
                                                 const float4* __restrict__ ae4, int layer,
                                                 const float* __restrict__ al, const float* __restrict__ ar,
                                                 const float* __restrict__ ce, const float* __restrict__ xl,
                                                 const float* __restrict__ bias, const float* __restrict__ hprev,
                                                 float* __restrict__ hnew,
                                                 float* __restrict__ bnsum, float* __restrict__ bnsumsq, int do_bn) {
    __shared__ float sa[256], sb_[256];
    int t = threadIdx.x;
    int w = t >> 6, lane = t & 63;
    int n = blockIdx.x * 4 + w;
    float v = 0.f;
    if (n < NN) {
        int r0 = rowptr[n], r1 = rowptr[n + 1];
        float arn0 = ar[n * 2 + 0], arn1 = ar[n * 2 + 1];
        // pass 1: per-lane strided max, then wave reduce
        float m0 = -3.4e38f, m1 = -3.4e38f;
        for (int p = r0 + lane; p < r1; p += 64) {
            int sb = csr_sb[p];
            int s = sb & 0xFFFFF, b = sb >> 20;
            float4 ae = ae4[p];
            float e0 = layer ? ae.z : ae.x;
            float e1 = layer ? ae.w : ae.y;
            float a0 = al[s * 2 + 0] + arn0 + e0 + ce[b * 2 + 0];
            float a1 = al[s * 2 + 1] + arn1 + e1 + ce[b * 2 + 1];
            a0 = (a0 > 0.f) ? a0 : SLOPE * a0;
            a1 = (a1 > 0.f) ? a1 : SLOPE * a1;
            m0 = fmaxf(m0, a0); m1 = fmaxf(m1, a1);
        }
        for (int off = 32; off > 0; off >>= 1) {
            m0 = fmaxf(m0, __shfl_xor(m0, off));
            m1 = fmaxf(m1, __shfl_xor(m1, off));
        }
        // pass 2: serial over edges, lanes cover channels
        float acc0 = 0.f, acc1 = 0.f, s0 = 0.f, s1 = 0.f;
        for (int p = r0; p < r1; ++p) {
            int sb = csr_sb[p];
            int s = sb & 0xFFFFF, b = sb >> 20;
            float4 ae = ae4[p];
            float e0 = layer ? ae.z : ae.x;
            float e1 = layer ? ae.w : ae.y;
            float a0 = al[s * 2 + 0] + arn0 + e0 + ce[b * 2 + 0];
            float a1 = al[s * 2 + 1] + arn1 + e1 + ce[b * 2 + 1];
            a0 = (a0 > 0.f) ? a0 : SLOPE * a0;
            a1 = (a1 > 0.f) ? a1 : SLOPE * a1;
            float ex0 = expf(a0 - m0);
            float ex1 = expf(a1 - m1);
            s0 += ex0; s1 += ex1;
            acc0 += ex0 * xl[(size_t)s * 128 + lane];
            acc1 += ex1 * xl[(size_t)s * 128 + 64 + lane];
        }
        v = 0.5f * (acc0 / (s0 + 1e-16f) + acc1 / (s1 + 1e-16f)) + bias[lane] + hprev[(size_t)n * 64 + lane];
        hnew[(size_t)n * 64 + lane] = v;
    }
    if (do_bn) {
        sa[t] = (n < NN) ? v : 0.f;
        sb_[t] = (n < NN) ? v * v : 0.f;
        __syncthreads();
        if (t < 64) {
            float a = sa[t] + sa[t + 64] + sa[t + 128] + sa[t + 192];
            float b = sb_[t] + sb_[t + 64] + sb_[t + 128] + sb_[t + 192];
            atomicAdd(&bnsum[t], a);
            atomicAdd(&bnsumsq[t], b);
        }
    }
}

// ---------- batchnorm + relu in place ----------
__global__ __launch_bounds__(256) void k_bn(float* __restrict__ hbuf, const float* __restrict__ bnsum,
                                            const float* __restrict__ bnsumsq,
                                            const float* __restrict__ gamma, const float* __restrict__ beta) {
    int idx = blockIdx.x * 256 + threadIdx.x;
    if (idx >= NN * 64) return;
    int c = idx & 63;
    float mu = bnsum[c] * (1.f / NN);
    float var = bnsumsq[c] * (1.f / NN) - mu * mu;
    float v = (hbuf[idx] - mu) * rsqrtf(var + BN_EPS) * gamma[c] + beta[c];
    hbuf[idx] = (v > 0.f) ? v : 0.f;
}

extern "C" void kernel_launch(void* const* d_in, const int* in_sizes, int n_in,
                              void* d_out, int out_size, void* d_ws, size_t ws_size,
                              hipStream_t stream) {
    (void)in_sizes; (void)n_in; (void)out_size; (void)ws_size;
    const float* x     = (const float*)d_in[0];
    const int*   eidx  = (const int*)d_in[1];
    const float* eattr = (const float*)d_in[2];
    const float* instr = (const float*)d_in[3];
    const int*   batch = (const int*)d_in[4];
    const float* W_l   = (const float*)d_in[5];
    const float* W_e   = (const float*)d_in[6];
    const float* att_l = (const float*)d_in[7];
    const float* att_r = (const float*)d_in[8];
    const float* att_e = (const float*)d_in[9];
    const float* bias  = (const float*)d_in[10];
    const float* bn_g  = (const float*)d_in[11];
    const float* bn_b  = (const float*)d_in[12];
    float* out = (float*)d_out;

    const int* src = eidx;
    const int* dst = eidx + NE;

    // ---- workspace layout (floats/ints, 4B units) ----
    char* ws = (char*)d_ws;
    int*    deg    = (int*)ws;                 ws += NN * 4;
    int*    rowptr = (int*)ws;                 ws += (NN + 1) * 4;
    int*    cursor = (int*)ws;                 ws += NN * 4;
    int*    perm   = (int*)ws;                 ws += (size_t)NE * 4;
    int*    csr_sb = (int*)ws;                 ws += (size_t)NE * 4;
    float4* ae4    = (float4*)ws;              ws += (size_t)NE * 16;
    float*  xl     = (float*)ws;               ws += (size_t)NN * 128 * 4;
    float*  al     = (float*)ws;               ws += NN * 2 * 4;
    float*  ar     = (float*)ws;               ws += NN * 2 * 4;
    float*  insl   = (float*)ws;               ws += 128 * 128 * 4;
    float*  ve01   = (float*)ws;               ws += 256 * 4;
    float*  w2e01  = (float*)ws;               ws += 256 * 4;
    float*  ce     = (float*)ws;               ws += 256 * 4;
    float*  hbuf   = (float*)ws;               ws += (size_t)NN * 64 * 4;
    float*  bnsum  = (float*)ws;               ws += 64 * 4;
    float*  bnsumsq= (float*)ws;               ws += 64 * 4;

    // ---- CSR build (per call; edge_index identical across layers) ----
    hipMemsetAsync(deg, 0, NN * 4, stream);
    hipMemsetAsync(bnsum, 0, 128 * 4, stream); // bnsum + bnsumsq
    k_hist<<<(NE + 255) / 256, 256, 0, stream>>>(dst, deg);
    k_scan<<<1, 256, 0, stream>>>(deg, rowptr, cursor);
    k_scatter<<<(NE + 255) / 256, 256, 0, stream>>>(src, dst, batch, cursor, perm, csr_sb);

    // ---- both layers' edge dot vectors, then one pass over edge_attr ----
    k_p1<<<2, 256, 0, stream>>>(W_e, att_e, ve01, w2e01);
    k_edot<<<(NE + 255) / 256, 256, 0, stream>>>(eattr, perm, ve01, ae4);

    for (int i = 0; i < 2; ++i) {
        const float* hcur  = (i == 0) ? x : hbuf;
        const float* hprev = hcur;
        float* hnew = (i == 0) ? hbuf : out;
        const float* Wl_i  = W_l + (size_t)i * 128 * 128;
        const float* ins_i = instr + (size_t)i * NB * 64;

        k_p2<<<65, 256, 0, stream>>>(ins_i, Wl_i, w2e01 + i * 128, insl, ce);
        k_node<<<(NN + 7) / 8, 256, 0, stream>>>(hcur, Wl_i, insl, batch,
                                                 att_l + i * 128, att_r + i * 128, xl, al, ar);
        k_nodeagg<<<(NN + 3) / 4, 256, 0, stream>>>(rowptr, csr_sb, ae4, i, al, ar, ce, xl,
                                                    bias + i * 64, hprev, hnew,
                                                    bnsum, bnsumsq, (i == 0) ? 1 : 0);
        if (i == 0) {
            k_bn<<<(NN * 64 + 255) / 256, 256, 0, stream>>>(hbuf, bnsum, bnsumsq, bn_g, bn_b);
        }
    }
}

// Round 3
// 515.496 us; speedup vs baseline: 1.5189x; 1.0643x over previous
//
#include <hip/hip_runtime.h>
#include <math.h>

#define NN 20000
#define NE 320000
#define NB 128
#define SLOPE 0.2f
#define BN_EPS 1e-5f

// ---------- CSR build ----------
__global__ __launch_bounds__(256) void k_hist(const int* __restrict__ dst, int* __restrict__ deg) {
    int e = blockIdx.x * 256 + threadIdx.x;
    if (e < NE) atomicAdd(&deg[dst[e]], 1);
}

__global__ __launch_bounds__(256) void k_scan(const int* __restrict__ deg, int* __restrict__ rowptr,
                                              int* __restrict__ cursor) {
    __shared__ int ssum[256];
    __shared__ int soff[256];
    const int CH = 79; // 256*79 = 20224 >= NN
    int t = threadIdx.x;
    int base = t * CH;
    int s = 0;
    for (int i = 0; i < CH; ++i) { int idx = base + i; if (idx < NN) s += deg[idx]; }
    ssum[t] = s;
    __syncthreads();
    if (t == 0) {
        int run = 0;
        for (int i = 0; i < 256; ++i) { soff[i] = run; run += ssum[i]; }
        rowptr[NN] = run;
    }
    __syncthreads();
    int run = soff[t];
    for (int i = 0; i < CH; ++i) {
        int idx = base + i;
        if (idx < NN) { rowptr[idx] = run; cursor[idx] = run; run += deg[idx]; }
    }
}

// perm[e] = CSR slot; csr_sb[slot] = src | (batch[src] << 20)
__global__ __launch_bounds__(256) void k_scatter(const int* __restrict__ src, const int* __restrict__ dst,
                                                 const int* __restrict__ batch,
                                                 int* __restrict__ cursor, int* __restrict__ perm,
                                                 int* __restrict__ csr_sb) {
    int e = blockIdx.x * 256 + threadIdx.x;
    if (e >= NE) return;
    int d = dst[e];
    int pos = atomicAdd(&cursor[d], 1);
    perm[e] = pos;
    int s = src[e];
    csr_sb[pos] = s | (batch[s] << 20);
}

// ---------- per-layer precompute ----------
__global__ __launch_bounds__(256) void k_p1(const float* __restrict__ We, const float* __restrict__ atte,
                                            float* __restrict__ ve01, float* __restrict__ w2e01) {
    int L = blockIdx.x;
    const float* WeL = We + (size_t)L * 128 * 128;
    const float* aeL = atte + L * 128;
    int t = threadIdx.x;
    int h = (t >> 6) & 1;
    int k = t & 63;
    int row = (t < 128) ? k : (64 + k);
    float acc = 0.f;
    for (int c = 0; c < 64; ++c) acc += WeL[row * 128 + h * 64 + c] * aeL[h * 64 + c];
    if (t < 128) ve01[L * 128 + t] = acc;
    else        w2e01[L * 128 + (t - 128)] = acc;
}

__global__ __launch_bounds__(256) void k_p2(const float* __restrict__ ins, const float* __restrict__ Wl,
                                            const float* __restrict__ w2e,
                                            float* __restrict__ insl, float* __restrict__ ce) {
    int t = threadIdx.x;
    if (blockIdx.x < 64) {
        int idx = blockIdx.x * 256 + t;
        int b = idx >> 7, j = idx & 127;
        float acc = 0.f;
        for (int k = 0; k < 64; ++k) acc += ins[b * 64 + k] * Wl[(64 + k) * 128 + j];
        insl[idx] = acc;
    } else {
        int b = t >> 1, h = t & 1;
        float acc = 0.f;
        for (int k = 0; k < 64; ++k) acc += ins[b * 64 + k] * w2e[h * 64 + k];
        ce[t] = acc;
    }
}

// ---------- edge dot for BOTH layers, written in CSR order ----------
__global__ __launch_bounds__(256) void k_edot(const float* __restrict__ eattr, const int* __restrict__ perm,
                                              const float* __restrict__ ve01, float4* __restrict__ ae4) {
    __shared__ float sv[256];
    int t = threadIdx.x;
    sv[t] = ve01[t];
    __syncthreads();
    int e = blockIdx.x * 256 + t;
    if (e >= NE) return;
    const float4* row = (const float4*)(eattr + (size_t)e * 64);
    float a00 = 0.f, a01 = 0.f, a10 = 0.f, a11 = 0.f;
#pragma unroll
    for (int q = 0; q < 16; ++q) {
        float4 f = row[q];
        int k = q * 4;
        a00 += f.x * sv[k] + f.y * sv[k + 1] + f.z * sv[k + 2] + f.w * sv[k + 3];
        a01 += f.x * sv[64 + k] + f.y * sv[64 + k + 1] + f.z * sv[64 + k + 2] + f.w * sv[64 + k + 3];
        a10 += f.x * sv[128 + k] + f.y * sv[128 + k + 1] + f.z * sv[128 + k + 2] + f.w * sv[128 + k + 3];
        a11 += f.x * sv[192 + k] + f.y * sv[192 + k + 1] + f.z * sv[192 + k + 2] + f.w * sv[192 + k + 3];
    }
    ae4[perm[e]] = make_float4(a00, a01, a10, a11);
}

// ---------- node linear + attention coefficients ----------
__global__ __launch_bounds__(256) void k_node(const float* __restrict__ hcur, const float* __restrict__ Wl,
                                              const float* __restrict__ insl, const int* __restrict__ batch,
                                              const float* __restrict__ attl, const float* __restrict__ attr_,
                                              float* __restrict__ xl, float* __restrict__ al, float* __restrict__ ar) {
    __shared__ float sh[8 * 64];
    int t = threadIdx.x;
    int row0 = blockIdx.x * 8;
    for (int idx = t; idx < 512; idx += 256) {
        int r = idx >> 6, k = idx & 63;
        int n = row0 + r;
        sh[idx] = (n < NN) ? hcur[n * 64 + k] : 0.f;
    }
    __syncthreads();
    int w = t >> 6, lane = t & 63;
    int h = w & 1;
    int rbase = (w >> 1) * 4;
    int j = h * 64 + lane;
    float attlv = attl[j];
    float attrv = attr_[j];
    float acc0 = 0.f, acc1 = 0.f, acc2 = 0.f, acc3 = 0.f;
    for (int k = 0; k < 64; ++k) {
        float wv = Wl[k * 128 + j];
        acc0 += sh[(rbase + 0) * 64 + k] * wv;
        acc1 += sh[(rbase + 1) * 64 + k] * wv;
        acc2 += sh[(rbase + 2) * 64 + k] * wv;
        acc3 += sh[(rbase + 3) * 64 + k] * wv;
    }
    float accs[4] = {acc0, acc1, acc2, acc3};
    for (int rr = 0; rr < 4; ++rr) {
        int n = row0 + rbase + rr;
        if (n >= NN) break;
        int b = batch[n];
        float v = accs[rr] + insl[b * 128 + j];
        xl[(size_t)n * 128 + j] = v;
        float pl = v * attlv, pr = v * attrv;
        for (int off = 32; off > 0; off >>= 1) {
            pl += __shfl_xor(pl, off);
            pr += __shfl_xor(pr, off);
        }
        if (lane == 0) { al[n * 2 + h] = pl; ar[n * 2 + h] = pr; }
    }
}

// ---------- fused gather v2: register-resident edge state, shuffle-broadcast pass 2 ----------
// 1 wave per node; lane = channel (both heads via 2 accumulators). Online softmax across 64-edge chunks.
__global__ __launch_bounds__(256) void k_nodeagg(const int* __restrict__ rowptr, const int* __restrict__ csr_sb,
                                                 const float4* __restrict__ ae4, int layer,
                                                 const float2* __restrict__ al2, const float2* __restrict__ ar2,
                                                 const float2* __restrict__ ce2, const float* __restrict__ xl,
                                                 const float* __restrict__ bias, const float* __restrict__ hprev,
                                                 float* __restrict__ hnew,
                                                 float* __restrict__ bnsum, float* __restrict__ bnsumsq, int do_bn) {
    __shared__ float sa[256], sb_[256];
    int t = threadIdx.x;
    int w = t >> 6, lane = t & 63;
    int n = blockIdx.x * 4 + w;
    float v = 0.f;
    if (n < NN) {
        int r0 = rowptr[n], r1 = rowptr[n + 1];
        float2 arn = ar2[n];
        float m0 = -3.4e38f, m1 = -3.4e38f, s0 = 0.f, s1 = 0.f, acc0 = 0.f, acc1 = 0.f;
        for (int p0 = r0; p0 < r1; p0 += 64) {
            int cnt = min(64, r1 - p0);
            int s_l = 0;
            float a0 = -3.4e38f, a1 = -3.4e38f;
            if (lane < cnt) {
                int sb = csr_sb[p0 + lane];
                s_l = sb & 0xFFFFF;
                int b = sb >> 20;
                float4 ae = ae4[p0 + lane];
                float2 als = al2[s_l];
                float2 cb = ce2[b];
                a0 = als.x + arn.x + (layer ? ae.z : ae.x) + cb.x;
                a1 = als.y + arn.y + (layer ? ae.w : ae.y) + cb.y;
                a0 = (a0 > 0.f) ? a0 : SLOPE * a0;
                a1 = (a1 > 0.f) ? a1 : SLOPE * a1;
            }
            float cm0 = a0, cm1 = a1;
            for (int off = 32; off > 0; off >>= 1) {
                cm0 = fmaxf(cm0, __shfl_xor(cm0, off));
                cm1 = fmaxf(cm1, __shfl_xor(cm1, off));
            }
            float nm0 = fmaxf(m0, cm0), nm1 = fmaxf(m1, cm1);
            float sc0 = __expf(m0 - nm0), sc1 = __expf(m1 - nm1); // first chunk: exp(-huge)=0, s/acc are 0
            float ex0 = (lane < cnt) ? __expf(a0 - nm0) : 0.f;
            float ex1 = (lane < cnt) ? __expf(a1 - nm1) : 0.f;
            float cs0 = ex0, cs1 = ex1;
            for (int off = 32; off > 0; off >>= 1) {
                cs0 += __shfl_xor(cs0, off);
                cs1 += __shfl_xor(cs1, off);
            }
            s0 = s0 * sc0 + cs0; s1 = s1 * sc1 + cs1;
            acc0 *= sc0; acc1 *= sc1;
            m0 = nm0; m1 = nm1;
            int j = 0;
            for (; j + 4 <= cnt; j += 4) {
                int sj0 = __shfl(s_l, j),     sj1 = __shfl(s_l, j + 1);
                int sj2 = __shfl(s_l, j + 2), sj3 = __shfl(s_l, j + 3);
                float e00 = __shfl(ex0, j),     e01 = __shfl(ex0, j + 1);
                float e02 = __shfl(ex0, j + 2), e03 = __shfl(ex0, j + 3);
                float e10 = __shfl(ex1, j),     e11 = __shfl(ex1, j + 1);
                float e12 = __shfl(ex1, j + 2), e13 = __shfl(ex1, j + 3);
                const float* q0 = xl + (size_t)sj0 * 128 + lane;
                const float* q1 = xl + (size_t)sj1 * 128 + lane;
                const float* q2 = xl + (size_t)sj2 * 128 + lane;
                const float* q3 = xl + (size_t)sj3 * 128 + lane;
                float x00 = q0[0], x01 = q0[64];
                float x10 = q1[0], x11 = q1[64];
                float x20 = q2[0], x21 = q2[64];
                float x30 = q3[0], x31 = q3[64];
                acc0 += e00 * x00 + e01 * x10 + e02 * x20 + e03 * x30;
                acc1 += e10 * x01 + e11 * x11 + e12 * x21 + e13 * x31;
            }
            for (; j < cnt; ++j) {
                int sj = __shfl(s_l, j);
                float e0 = __shfl(ex0, j), e1 = __shfl(ex1, j);
                const float* q = xl + (size_t)sj * 128 + lane;
                acc0 += e0 * q[0];
                acc1 += e1 * q[64];
            }
        }
        v = 0.5f * (acc0 / (s0 + 1e-16f) + acc1 / (s1 + 1e-16f)) + bias[lane] + hprev[(size_t)n * 64 + lane];
        hnew[(size_t)n * 64 + lane] = v;
    }
    if (do_bn) {
        sa[t] = (n < NN) ? v : 0.f;
        sb_[t] = (n < NN) ? v * v : 0.f;
        __syncthreads();
        if (t < 64) {
            float a = sa[t] + sa[t + 64] + sa[t + 128] + sa[t + 192];
            float b = sb_[t] + sb_[t + 64] + sb_[t + 128] + sb_[t + 192];
            atomicAdd(&bnsum[t], a);
            atomicAdd(&bnsumsq[t], b);
        }
    }
}

// ---------- batchnorm + relu in place ----------
__global__ __launch_bounds__(256) void k_bn(float* __restrict__ hbuf, const float* __restrict__ bnsum,
                                            const float* __restrict__ bnsumsq,
                                            const float* __restrict__ gamma, const float* __restrict__ beta) {
    int idx = blockIdx.x * 256 + threadIdx.x;
    if (idx >= NN * 64) return;
    int c = idx & 63;
    float mu = bnsum[c] * (1.f / NN);
    float var = bnsumsq[c] * (1.f / NN) - mu * mu;
    float v = (hbuf[idx] - mu) * rsqrtf(var + BN_EPS) * gamma[c] + beta[c];
    hbuf[idx] = (v > 0.f) ? v : 0.f;
}

extern "C" void kernel_launch(void* const* d_in, const int* in_sizes, int n_in,
                              void* d_out, int out_size, void* d_ws, size_t ws_size,
                              hipStream_t stream) {
    (void)in_sizes; (void)n_in; (void)out_size; (void)ws_size;
    const float* x     = (const float*)d_in[0];
    const int*   eidx  = (const int*)d_in[1];
    const float* eattr = (const float*)d_in[2];
    const float* instr = (const float*)d_in[3];
    const int*   batch = (const int*)d_in[4];
    const float* W_l   = (const float*)d_in[5];
    const float* W_e   = (const float*)d_in[6];
    const float* att_l = (const float*)d_in[7];
    const float* att_r = (const float*)d_in[8];
    const float* att_e = (const float*)d_in[9];
    const float* bias  = (const float*)d_in[10];
    const float* bn_g  = (const float*)d_in[11];
    const float* bn_b  = (const float*)d_in[12];
    float* out = (float*)d_out;

    const int* src = eidx;
    const int* dst = eidx + NE;

    char* ws = (char*)d_ws;
    int*    deg    = (int*)ws;                 ws += NN * 4;
    int*    rowptr = (int*)ws;                 ws += (NN + 1) * 4;
    int*    cursor = (int*)ws;                 ws += NN * 4;
    int*    perm   = (int*)ws;                 ws += (size_t)NE * 4;
    int*    csr_sb = (int*)ws;                 ws += (size_t)NE * 4;
    float4* ae4    = (float4*)ws;              ws += (size_t)NE * 16;
    float*  xl     = (float*)ws;               ws += (size_t)NN * 128 * 4;
    float*  al     = (float*)ws;               ws += NN * 2 * 4;
    float*  ar     = (float*)ws;               ws += NN * 2 * 4;
    float*  insl   = (float*)ws;               ws += 128 * 128 * 4;
    float*  ve01   = (float*)ws;               ws += 256 * 4;
    float*  w2e01  = (float*)ws;               ws += 256 * 4;
    float*  ce     = (float*)ws;               ws += 256 * 4;
    float*  hbuf   = (float*)ws;               ws += (size_t)NN * 64 * 4;
    float*  bnsum  = (float*)ws;               ws += 64 * 4;
    float*  bnsumsq= (float*)ws;               ws += 64 * 4;

    hipMemsetAsync(deg, 0, NN * 4, stream);
    hipMemsetAsync(bnsum, 0, 128 * 4, stream); // bnsum + bnsumsq
    k_hist<<<(NE + 255) / 256, 256, 0, stream>>>(dst, deg);
    k_scan<<<1, 256, 0, stream>>>(deg, rowptr, cursor);
    k_scatter<<<(NE + 255) / 256, 256, 0, stream>>>(src, dst, batch, cursor, perm, csr_sb);

    k_p1<<<2, 256, 0, stream>>>(W_e, att_e, ve01, w2e01);
    k_edot<<<(NE + 255) / 256, 256, 0, stream>>>(eattr, perm, ve01, ae4);

    for (int i = 0; i < 2; ++i) {
        const float* hcur  = (i == 0) ? x : hbuf;
        const float* hprev = hcur;
        float* hnew = (i == 0) ? hbuf : out;
        const float* Wl_i  = W_l + (size_t)i * 128 * 128;
        const float* ins_i = instr + (size_t)i * NB * 64;

        k_p2<<<65, 256, 0, stream>>>(ins_i, Wl_i, w2e01 + i * 128, insl, ce);
        k_node<<<(NN + 7) / 8, 256, 0, stream>>>(hcur, Wl_i, insl, batch,
                                                 att_l + i * 128, att_r + i * 128, xl, al, ar);
        k_nodeagg<<<(NN + 3) / 4, 256, 0, stream>>>(rowptr, csr_sb, ae4, i,
                                                    (const float2*)al, (const float2*)ar,
                                                    (const float2*)ce, xl,
                                                    bias + i * 64, hprev, hnew,
                                                    bnsum, bnsumsq, (i == 0) ? 1 : 0);
        if (i == 0) {
            k_bn<<<(NN * 64 + 255) / 256, 256, 0, stream>>>(hbuf, bnsum, bnsumsq, bn_g, bn_b);
        }
    }
}